// Round 5
// baseline (905986.133 us; speedup 1.0000x reference)
//
#include <hip/hip_runtime.h>
#include <stdint.h>

#define B_ 256
#define T_ 512
#define D_ 128
#define H_ 256

typedef __attribute__((ext_vector_type(8))) _Float16 half8;
typedef __attribute__((ext_vector_type(4))) float f32x4;

// ws layout (bytes)
#define WS_FLAG 0        // [16 groups][16 slices] epoch flags, 64 B apart (16 KB)
#define WS_PART 16384    // 16*256 floats fc partials (16 KB)
#define WS_CHK  32768    // placement-check: 16 ctr (128B apart) + 16 xcc + 16 mm
#define WS_H0   65536    // [2][256][256] f16 layer0 h double buffer
#define WS_H1   327680   // [2][256][256] f16 layer1 h double buffer

__device__ __forceinline__ float fast_sig(float x) {
    return 1.0f / (1.0f + __expf(-x));
}
__device__ __forceinline__ float fast_tanh(float x) {
    float xc = fminf(fmaxf(x, -30.0f), 30.0f);
    float e = __expf(-2.0f * xc);
    return (1.0f - e) / (1.0f + e);
}
__device__ __forceinline__ half8 cvt8(const float* p) {
    const f32x4* q = (const f32x4*)p;
    f32x4 a = q[0], b = q[1];
    half8 r;
    r[0] = (_Float16)a[0]; r[1] = (_Float16)a[1];
    r[2] = (_Float16)a[2]; r[3] = (_Float16)a[3];
    r[4] = (_Float16)b[0]; r[5] = (_Float16)b[1];
    r[6] = (_Float16)b[2]; r[7] = (_Float16)b[3];
    return r;
}
__device__ __forceinline__ half8 cvt8v(f32x4 a, f32x4 b) {
    half8 r;
    r[0] = (_Float16)a[0]; r[1] = (_Float16)a[1];
    r[2] = (_Float16)a[2]; r[3] = (_Float16)a[3];
    r[4] = (_Float16)b[0]; r[5] = (_Float16)b[1];
    r[6] = (_Float16)b[2]; r[7] = (_Float16)b[3];
    return r;
}

// ---- coherence-scoped primitives ----
// DEV=true : sc0 sc1 (device scope, meets at MALL) — placement-independent.
// DEV=false: sc0     (SE scope, bypasses L1, meets at the XCD's shared L2) —
//            valid only when all communicating wgs share an XCD (verified).
#define L8_BODY(CF, TAIL)                                                  \
    asm volatile(                                                          \
        "global_load_dwordx4 %0, %8, off " CF "\n\t"                       \
        "global_load_dwordx4 %1, %8, off offset:64 " CF "\n\t"             \
        "global_load_dwordx4 %2, %8, off offset:128 " CF "\n\t"            \
        "global_load_dwordx4 %3, %8, off offset:192 " CF "\n\t"            \
        "global_load_dwordx4 %4, %8, off offset:256 " CF "\n\t"            \
        "global_load_dwordx4 %5, %8, off offset:320 " CF "\n\t"            \
        "global_load_dwordx4 %6, %8, off offset:384 " CF "\n\t"            \
        "global_load_dwordx4 %7, %8, off offset:448 " CF TAIL              \
        : "=&v"(f[0]), "=&v"(f[1]), "=&v"(f[2]), "=&v"(f[3]),              \
          "=&v"(f[4]), "=&v"(f[5]), "=&v"(f[6]), "=&v"(f[7])               \
        : "v"(p) : "memory")

template<bool DEV>
__device__ __forceinline__ void load8h_nowait(const _Float16* p, half8* f) {
    if constexpr (DEV) L8_BODY("sc0 sc1", "");
    else               L8_BODY("sc0", "");
}
template<bool DEV>
__device__ __forceinline__ void load8h_wait(const _Float16* p, half8* f) {
    if constexpr (DEV) L8_BODY("sc0 sc1", "\n\ts_waitcnt vmcnt(0)");
    else               L8_BODY("sc0", "\n\ts_waitcnt vmcnt(0)");
}
template<bool DEV>
__device__ __forceinline__ void store_h(_Float16* p, float v) {
    union { _Float16 h; short s; } u;
    u.h = (_Float16)v;
    int vi = u.s;
    if constexpr (DEV)
        asm volatile("global_store_short %0, %1, off sc0 sc1" :: "v"(p), "v"(vi) : "memory");
    else
        asm volatile("global_store_short %0, %1, off sc0" :: "v"(p), "v"(vi) : "memory");
}
template<bool DEV>
__device__ __forceinline__ void store_flag(int* p, int v) {
    if constexpr (DEV)
        asm volatile("global_store_dword %0, %1, off sc0 sc1" :: "v"(p), "v"(v) : "memory");
    else
        asm volatile("global_store_dword %0, %1, off sc0" :: "v"(p), "v"(v) : "memory");
}
template<bool DEV>
__device__ __forceinline__ int load_flag(const int* p) {
    int v;
    if constexpr (DEV)
        asm volatile("global_load_dword %0, %1, off sc0 sc1\n\ts_waitcnt vmcnt(0)"
                     : "=&v"(v) : "v"(p) : "memory");
    else
        asm volatile("global_load_dword %0, %1, off sc0\n\ts_waitcnt vmcnt(0)"
                     : "=&v"(v) : "v"(p) : "memory");
    return v;
}

// Device-scope barrier (MALL atomics) — used only for the startup placement
// check (validated on HW in R2).
__device__ __forceinline__ void slow_bar(int* c, int target) {
    __hip_atomic_fetch_add(c, 1, __ATOMIC_RELEASE, __HIP_MEMORY_SCOPE_AGENT);
    int guard = 0;
    while (__hip_atomic_load(c, __ATOMIC_RELAXED, __HIP_MEMORY_SCOPE_AGENT) < target) {
        __builtin_amdgcn_s_sleep(1);
        if (++guard > 400000) break;
    }
    __builtin_amdgcn_fence(__ATOMIC_ACQUIRE, "agent");
}

__global__ void lstm_init(char* ws) {
    int* f = (int*)(ws + WS_FLAG);
    for (int i = threadIdx.x; i < 4096; i += 256) f[i] = 0;
    int* c = (int*)(ws + WS_CHK);
    for (int i = threadIdx.x; i < 1024; i += 256) c[i] = 0;
}

// Main recurrence loop, templated on coherence scope.
template<bool DEV>
__device__ __forceinline__ float lstm_loop(
    const float* __restrict__ xrow, const half8* wA, const half8* wB,
    float biasA, float biasB,
    _Float16* __restrict__ h0buf, _Float16* __restrict__ h1buf,
    int* __restrict__ flags, float* gbuf,
    int tid, int sl, int b0, int w, int row, int quad, int kb,
    int bb, int jj, int bglob, int j0, int len)
{
    float c0 = 0.f, c1 = 0.f, hsave = 0.f;

    // x fragments + xacc for step 0
    f32x4 xr[8];
    {
        const f32x4* q = (const f32x4*)xrow;
#pragma unroll
        for (int kt = 0; kt < 4; ++kt) { xr[2 * kt] = q[kt * 8]; xr[2 * kt + 1] = q[kt * 8 + 1]; }
    }
    f32x4 xacc = {0.f, 0.f, 0.f, 0.f};
#pragma unroll
    for (int kt = 0; kt < 4; ++kt)
        xacc = __builtin_amdgcn_mfma_f32_16x16x32_f16(cvt8v(xr[2 * kt], xr[2 * kt + 1]), wA[kt], xacc, 0, 0, 0);

    for (int u = 0; u <= T_; ++u) {
        // prefetch x for step u+1 (plain cached loads; complete under h-load wait)
        {
            const int tn = (u + 1 < T_) ? (u + 1) : (T_ - 1);
            const f32x4* q = (const f32x4*)(xrow + (size_t)tn * D_);
#pragma unroll
            for (int kt = 0; kt < 4; ++kt) { xr[2 * kt] = q[kt * 8]; xr[2 * kt + 1] = q[kt * 8 + 1]; }
        }

        f32x4 acc0 = xacc;
        f32x4 acc1 = {0.f, 0.f, 0.f, 0.f};

        if (u >= 1) {
            half8 hg[8];
            if (u >= 2)
                load8h_nowait<DEV>(h1buf + ((size_t)((u - 2) & 1) * B_ + (b0 + row)) * H_ + kb, hg);
            half8 hf[8];
            load8h_wait<DEV>(h0buf + ((size_t)((u - 1) & 1) * B_ + (b0 + row)) * H_ + kb, hf);
#pragma unroll
            for (int kt = 0; kt < 8; ++kt) {
                if (u < T_) acc0 = __builtin_amdgcn_mfma_f32_16x16x32_f16(hf[kt], wA[4 + kt], acc0, 0, 0, 0);
                acc1 = __builtin_amdgcn_mfma_f32_16x16x32_f16(hf[kt], wB[kt], acc1, 0, 0, 0);
            }
            if (u >= 2) {
#pragma unroll
                for (int kt = 0; kt < 8; ++kt)
                    acc1 = __builtin_amdgcn_mfma_f32_16x16x32_f16(hg[kt], wB[8 + kt], acc1, 0, 0, 0);
            }
        }

        // gates -> LDS (+bias). D-frag: value r is [m=quad*4+r][n=row]
        if (u < T_) {
#pragma unroll
            for (int r = 0; r < 4; ++r)
                gbuf[w * 256 + (quad * 4 + r) * 16 + row] = acc0[r] + biasA;
        }
        if (u >= 1) {
#pragma unroll
            for (int r = 0; r < 4; ++r)
                gbuf[1024 + w * 256 + (quad * 4 + r) * 16 + row] = acc1[r] + biasB;
        }
        __syncthreads();

        const int idx = bb * 16 + jj;
        if (u < T_) {
            float gi = fast_sig(gbuf[idx]);
            float gf = fast_sig(gbuf[256 + idx]);
            float gg = fast_tanh(gbuf[512 + idx]);
            float go = fast_sig(gbuf[768 + idx]);
            c0 = gf * c0 + gi * gg;
            float h0v = go * fast_tanh(c0);
            store_h<DEV>(&h0buf[((size_t)(u & 1) * B_ + bglob) * H_ + j0 + jj], h0v);
        }
        if (u >= 1) {
            float gi = fast_sig(gbuf[1024 + idx]);
            float gf = fast_sig(gbuf[1024 + 256 + idx]);
            float gg = fast_tanh(gbuf[1024 + 512 + idx]);
            float go = fast_sig(gbuf[1024 + 768 + idx]);
            c1 = gf * c1 + gi * gg;
            float h1v = go * fast_tanh(c1);
            store_h<DEV>(&h1buf[((size_t)((u - 1) & 1) * B_ + bglob) * H_ + j0 + jj], h1v);
            if (u == len) hsave = h1v;
        }

        // xacc for step u+1
        xacc[0] = 0.f; xacc[1] = 0.f; xacc[2] = 0.f; xacc[3] = 0.f;
#pragma unroll
        for (int kt = 0; kt < 4; ++kt)
            xacc = __builtin_amdgcn_mfma_f32_16x16x32_f16(cvt8v(xr[2 * kt], xr[2 * kt + 1]), wA[kt], xacc, 0, 0, 0);

        // ---- group barrier: spread flag lines at the scope's coherence pt ----
        if (u < T_) {
            asm volatile("s_waitcnt vmcnt(0)" ::: "memory");  // h stores acked
            __syncthreads();
            if (tid == 0) store_flag<DEV>(&flags[sl * 16], u + 1);
            const int* fp = &flags[(tid & 15) * 16];
            const int target = u + 1;
            int guard = 0;
            while (true) {
                int v = load_flag<DEV>(fp);
                if (__all(v >= target)) break;
                if (++guard > (1 << 14)) break;  // bounded: fail loud, never hang
            }
        }
    }
    return hsave;
}

// grid 256 wgs x 256 thr. wg = (batch group g = blk&15) x (hidden slice sl = blk>>4)
// wave w = gate (i,f,g,o); weights pinned in regs as f16 MFMA B-frags.
// Layer-pipelined: iter u does layer0 step u (u<T) and layer1 step u-1 (u>=1).
// h + flags exchanged at the XCD L2 (sc0) when the group is XCD-local
// (runtime-verified via HW_REG_XCC_ID), else at MALL (sc0 sc1). G16-safe.
__global__ __launch_bounds__(256, 1) void lstm_main(
    const float* __restrict__ x, const int* __restrict__ mask,
    const float* __restrict__ Wih0, const float* __restrict__ Whh0,
    const float* __restrict__ bih0, const float* __restrict__ bhh0,
    const float* __restrict__ Wih1, const float* __restrict__ Whh1,
    const float* __restrict__ bih1, const float* __restrict__ bhh1,
    const float* __restrict__ fcw, char* __restrict__ ws)
{
    const int tid  = threadIdx.x;
    const int blk  = blockIdx.x;
    const int g    = blk & 15;    // batch group: blk%16 -> same XCD under round-robin
    const int sl   = blk >> 4;    // hidden slice
    const int b0   = g * 16;
    const int j0   = sl * 16;
    const int w    = tid >> 6;
    const int lane = tid & 63;
    const int row  = lane & 15;
    const int quad = lane >> 4;
    const int kb   = quad * 8;

    int*      flags    = (int*)(ws + WS_FLAG) + g * 256;
    float*    partials = (float*)(ws + WS_PART);
    int*      chk      = (int*)(ws + WS_CHK);
    _Float16* h0buf    = (_Float16*)(ws + WS_H0);
    _Float16* h1buf    = (_Float16*)(ws + WS_H1);

    __shared__ float gbuf[2048];
    __shared__ int s_fast;

    // ---- pin weights in registers (f16 B-frags), n = gate row ----
    const int n = w * H_ + j0 + row;
    half8 wA[12], wB[16];
#pragma unroll
    for (int kt = 0; kt < 4; ++kt) wA[kt]     = cvt8(&Wih0[(size_t)n * D_ + kt * 32 + kb]);
#pragma unroll
    for (int kt = 0; kt < 8; ++kt) wA[4 + kt] = cvt8(&Whh0[(size_t)n * H_ + kt * 32 + kb]);
#pragma unroll
    for (int kt = 0; kt < 8; ++kt) wB[kt]     = cvt8(&Wih1[(size_t)n * H_ + kt * 32 + kb]);
#pragma unroll
    for (int kt = 0; kt < 8; ++kt) wB[8 + kt] = cvt8(&Whh1[(size_t)n * H_ + kt * 32 + kb]);
    const float biasA = bih0[n] + bhh0[n];
    const float biasB = bih1[n] + bhh1[n];

    const int bb    = tid >> 4;
    const int jj    = tid & 15;
    const int bglob = b0 + bb;

    int len = 0;
    {
        const int* mrow = mask + (size_t)bglob * T_ + jj * 32;
#pragma unroll
        for (int q = 0; q < 32; ++q) len += mrow[q];
#pragma unroll
        for (int o = 1; o < 16; o <<= 1) len += __shfl_xor(len, o, 16);
    }

    // ---- startup: verify the 16 wgs of this group share an XCD ----
    if (tid == 0) {
        int xcc;
        asm volatile("s_getreg_b32 %0, hwreg(20, 0, 4)" : "=s"(xcc));  // HW_REG_XCC_ID
        int* ctr = chk + g * 32;       // 128 B apart
        int* xcs = chk + 512 + g;      // leader ids
        int* mm  = chk + 528 + g;      // mismatch flags
        if (sl == 0)
            __hip_atomic_store(xcs, xcc, __ATOMIC_RELAXED, __HIP_MEMORY_SCOPE_AGENT);
        slow_bar(ctr, 16);
        if (__hip_atomic_load(xcs, __ATOMIC_RELAXED, __HIP_MEMORY_SCOPE_AGENT) != xcc)
            __hip_atomic_fetch_or(mm, 1, __ATOMIC_RELAXED, __HIP_MEMORY_SCOPE_AGENT);
        slow_bar(ctr, 32);
        s_fast = (__hip_atomic_load(mm, __ATOMIC_RELAXED, __HIP_MEMORY_SCOPE_AGENT) == 0);
    }
    __syncthreads();
    const bool fast = (s_fast != 0);

    const float* xrow = x + (size_t)(b0 + row) * T_ * D_ + kb;
    float hsave;
    if (fast)
        hsave = lstm_loop<false>(xrow, wA, wB, biasA, biasB, h0buf, h1buf, flags, gbuf,
                                 tid, sl, b0, w, row, quad, kb, bb, jj, bglob, j0, len);
    else
        hsave = lstm_loop<true>(xrow, wA, wB, biasA, biasB, h0buf, h1buf, flags, gbuf,
                                tid, sl, b0, w, row, quad, kb, bb, jj, bglob, j0, len);

    float part = hsave * fcw[j0 + jj];
#pragma unroll
    for (int o = 1; o < 16; o <<= 1) part += __shfl_xor(part, o, 16);
    if (jj == 0) partials[sl * B_ + bglob] = part;
}

__global__ void lstm_fc(const float* __restrict__ fcb, const char* __restrict__ ws,
                        float* __restrict__ out) {
    const int b = threadIdx.x;
    const float* partials = (const float*)(ws + WS_PART);
    float s = fcb[0];
#pragma unroll
    for (int sl = 0; sl < 16; ++sl) s += partials[sl * B_ + b];
    out[b] = s;
}

extern "C" void kernel_launch(void* const* d_in, const int* in_sizes, int n_in,
                              void* d_out, int out_size, void* d_ws, size_t ws_size,
                              hipStream_t stream) {
    const float* xx    = (const float*)d_in[0];
    const int*   mask  = (const int*)d_in[1];
    const float* Wih0  = (const float*)d_in[2];
    const float* Whh0  = (const float*)d_in[3];
    const float* bih0  = (const float*)d_in[4];
    const float* bhh0  = (const float*)d_in[5];
    const float* Wih1  = (const float*)d_in[6];
    const float* Whh1  = (const float*)d_in[7];
    const float* bih1  = (const float*)d_in[8];
    const float* bhh1  = (const float*)d_in[9];
    const float* fcw   = (const float*)d_in[10];
    const float* fcb   = (const float*)d_in[11];

    lstm_init<<<dim3(1), dim3(256), 0, stream>>>((char*)d_ws);
    lstm_main<<<dim3(256), dim3(256), 0, stream>>>(
        xx, mask, Wih0, Whh0, bih0, bhh0, Wih1, Whh1, bih1, bhh1, fcw, (char*)d_ws);
    lstm_fc<<<dim3(1), dim3(256), 0, stream>>>(fcb, (const char*)d_ws, (float*)d_out);
}

// Round 6
// 2014.602 us; speedup vs baseline: 449.7098x; 449.7098x over previous
//
#include <hip/hip_runtime.h>
#include <stdint.h>

#define B_ 256
#define T_ 512
#define D_ 128
#define H_ 256

typedef __attribute__((ext_vector_type(8))) _Float16 half8;
typedef __attribute__((ext_vector_type(4))) float f32x4;
typedef __attribute__((ext_vector_type(4))) int i32x4;

// ws layout (bytes)
#define WS_PART 0                      // 16*256 floats fc partials
#define WS_H0   65536                  // [2][256][256] u32 (epoch<<16 | f16) layer0 h
#define WS_H1   (65536 + 2*B_*H_*4)    // [2][256][256] u32 layer1 h
// total ~1.06 MB

__device__ __forceinline__ float fast_sig(float x) {
    return 1.0f / (1.0f + __expf(-x));
}
__device__ __forceinline__ float fast_tanh(float x) {
    float xc = fminf(fmaxf(x, -30.0f), 30.0f);
    float e = __expf(-2.0f * xc);
    return (1.0f - e) / (1.0f + e);
}
__device__ __forceinline__ half8 cvt8(const float* p) {
    const f32x4* q = (const f32x4*)p;
    f32x4 a = q[0], b = q[1];
    half8 r;
    r[0] = (_Float16)a[0]; r[1] = (_Float16)a[1];
    r[2] = (_Float16)a[2]; r[3] = (_Float16)a[3];
    r[4] = (_Float16)b[0]; r[5] = (_Float16)b[1];
    r[6] = (_Float16)b[2]; r[7] = (_Float16)b[3];
    return r;
}

// ---- MALL-coherent (sc0 sc1) primitives — the ONLY verified cross-CU path ----
// Poll load: this wave's quarter = 2 k-tiles of h0 (via p0) + 2 of h1 (via p1).
// Each tile = 8 dwords/lane at +0/+16; tile stride 128 B.
__device__ __forceinline__ void poll8(const unsigned* p0, const unsigned* p1, i32x4* r) {
    asm volatile(
        "global_load_dwordx4 %0, %8, off sc0 sc1\n\t"
        "global_load_dwordx4 %1, %8, off offset:16 sc0 sc1\n\t"
        "global_load_dwordx4 %2, %8, off offset:128 sc0 sc1\n\t"
        "global_load_dwordx4 %3, %8, off offset:144 sc0 sc1\n\t"
        "global_load_dwordx4 %4, %9, off sc0 sc1\n\t"
        "global_load_dwordx4 %5, %9, off offset:16 sc0 sc1\n\t"
        "global_load_dwordx4 %6, %9, off offset:128 sc0 sc1\n\t"
        "global_load_dwordx4 %7, %9, off offset:144 sc0 sc1\n\t"
        "s_waitcnt vmcnt(0)"
        : "=&v"(r[0]), "=&v"(r[1]), "=&v"(r[2]), "=&v"(r[3]),
          "=&v"(r[4]), "=&v"(r[5]), "=&v"(r[6]), "=&v"(r[7])
        : "v"(p0), "v"(p1) : "memory");
}
__device__ __forceinline__ void store_dw_mall(unsigned* p, unsigned v) {
    asm volatile("global_store_dword %0, %1, off sc0 sc1" :: "v"(p), "v"(v) : "memory");
}

// grid 256 wgs x 256 thr. wg = (batch group g = blk&15) x (hidden slice sl = blk>>4)
// wave w = gate (i,f,g,o); weights pinned in regs as f16 MFMA B-frags.
// Layer-pipelined: iter u does layer0 step u (u<T) and layer1 step u-1 (u>=1).
// NO barriers/flags/atomics: h elements carry their epoch; consumers poll the
// data itself until all epochs match. Fire-and-forget producer stores.
__global__ __launch_bounds__(256, 1) void lstm_main(
    const float* __restrict__ x, const int* __restrict__ mask,
    const float* __restrict__ Wih0, const float* __restrict__ Whh0,
    const float* __restrict__ bih0, const float* __restrict__ bhh0,
    const float* __restrict__ Wih1, const float* __restrict__ Whh1,
    const float* __restrict__ bih1, const float* __restrict__ bhh1,
    const float* __restrict__ fcw, char* __restrict__ ws)
{
    const int tid  = threadIdx.x;
    const int blk  = blockIdx.x;
    const int g    = blk & 15;    // batch group
    const int sl   = blk >> 4;    // hidden slice
    const int b0   = g * 16;
    const int j0   = sl * 16;
    const int w    = tid >> 6;
    const int lane = tid & 63;
    const int row  = lane & 15;
    const int quad = lane >> 4;
    const int kb   = quad * 8;

    float*    partials = (float*)(ws + WS_PART);
    unsigned* h0u      = (unsigned*)(ws + WS_H0);
    unsigned* h1u      = (unsigned*)(ws + WS_H1);

    __shared__ float gbuf[2048];
    __shared__ __align__(16) _Float16 hsh0[16 * 264];  // [row][k], +8 pad
    __shared__ __align__(16) _Float16 hsh1[16 * 264];

    // ---- pin weights in registers (f16 B-frags), n = gate row ----
    const int n = w * H_ + j0 + row;
    half8 wA[12], wB[16];
#pragma unroll
    for (int kt = 0; kt < 4; ++kt) wA[kt]     = cvt8(&Wih0[(size_t)n * D_ + kt * 32 + kb]);
#pragma unroll
    for (int kt = 0; kt < 8; ++kt) wA[4 + kt] = cvt8(&Whh0[(size_t)n * H_ + kt * 32 + kb]);
#pragma unroll
    for (int kt = 0; kt < 8; ++kt) wB[kt]     = cvt8(&Wih1[(size_t)n * H_ + kt * 32 + kb]);
#pragma unroll
    for (int kt = 0; kt < 8; ++kt) wB[8 + kt] = cvt8(&Whh1[(size_t)n * H_ + kt * 32 + kb]);
    const float biasA = bih0[n] + bhh0[n];
    const float biasB = bih1[n] + bhh1[n];

    const int bb    = tid >> 4;
    const int jj    = tid & 15;
    const int bglob = b0 + bb;

    int len = 0;
    {
        const int* mrow = mask + (size_t)bglob * T_ + jj * 32;
#pragma unroll
        for (int q = 0; q < 32; ++q) len += mrow[q];
#pragma unroll
        for (int o = 1; o < 16; o <<= 1) len += __shfl_xor(len, o, 16);
    }

    float c0 = 0.f, c1 = 0.f, hsave = 0.f;

    // xacc for step 0
    const float* xrow = x + (size_t)(b0 + row) * T_ * D_ + kb;
    f32x4 xacc = {0.f, 0.f, 0.f, 0.f};
#pragma unroll
    for (int kt = 0; kt < 4; ++kt)
        xacc = __builtin_amdgcn_mfma_f32_16x16x32_f16(cvt8(xrow + kt * 32), wA[kt], xacc, 0, 0, 0);

    for (int u = 0; u <= T_; ++u) {
        half8 a0[8], a1[8];

        if (u >= 1) {
            // ---- poll this wave's quarter: h0 tiles {2w,2w+1}, h1 same ----
            const unsigned tag0 = (unsigned)u << 16;
            const unsigned tag1 = (u >= 2) ? ((unsigned)(u - 1) << 16) : tag0;
            const unsigned* p0 = h0u + ((size_t)((u - 1) & 1) * B_ + (b0 + row)) * H_ + w * 64 + quad * 8;
            const unsigned* p1 = (u >= 2)
                ? h1u + ((size_t)(u & 1) * B_ + (b0 + row)) * H_ + w * 64 + quad * 8
                : p0;
            i32x4 r[8];
            int guard = 0;
            while (true) {
                poll8(p0, p1, r);
                unsigned m = 0;
#pragma unroll
                for (int i = 0; i < 4; ++i) {
                    m |= ((unsigned)r[i][0] ^ tag0); m |= ((unsigned)r[i][1] ^ tag0);
                    m |= ((unsigned)r[i][2] ^ tag0); m |= ((unsigned)r[i][3] ^ tag0);
                }
#pragma unroll
                for (int i = 4; i < 8; ++i) {
                    m |= ((unsigned)r[i][0] ^ tag1); m |= ((unsigned)r[i][1] ^ tag1);
                    m |= ((unsigned)r[i][2] ^ tag1); m |= ((unsigned)r[i][3] ^ tag1);
                }
                if (__all((m & 0xFFFF0000u) == 0)) break;
                if (++guard > (1 << 15)) break;  // bounded: fail loud, never hang
            }
            // ---- unpack f16 payloads -> LDS (wave's 2 tiles of each layer) ----
#pragma unroll
            for (int t = 0; t < 2; ++t) {
                i32x4 pk;
                pk[0] = (r[2 * t][0] & 0xFFFF) | (r[2 * t][1] << 16);
                pk[1] = (r[2 * t][2] & 0xFFFF) | (r[2 * t][3] << 16);
                pk[2] = (r[2 * t + 1][0] & 0xFFFF) | (r[2 * t + 1][1] << 16);
                pk[3] = (r[2 * t + 1][2] & 0xFFFF) | (r[2 * t + 1][3] << 16);
                *(i32x4*)(hsh0 + row * 264 + w * 64 + t * 32 + quad * 8) = pk;
            }
            if (u >= 2) {
#pragma unroll
                for (int t = 0; t < 2; ++t) {
                    i32x4 pk;
                    pk[0] = (r[4 + 2 * t][0] & 0xFFFF) | (r[4 + 2 * t][1] << 16);
                    pk[1] = (r[4 + 2 * t][2] & 0xFFFF) | (r[4 + 2 * t][3] << 16);
                    pk[2] = (r[5 + 2 * t][0] & 0xFFFF) | (r[5 + 2 * t][1] << 16);
                    pk[3] = (r[5 + 2 * t][2] & 0xFFFF) | (r[5 + 2 * t][3] << 16);
                    *(i32x4*)(hsh1 + row * 264 + w * 64 + t * 32 + quad * 8) = pk;
                }
            }
            __syncthreads();  // hsh complete
            // ---- read A-frags from LDS ----
#pragma unroll
            for (int kt = 0; kt < 8; ++kt)
                a0[kt] = *(const half8*)(hsh0 + row * 264 + kt * 32 + quad * 8);
            if (u >= 2) {
#pragma unroll
                for (int kt = 0; kt < 8; ++kt)
                    a1[kt] = *(const half8*)(hsh1 + row * 264 + kt * 32 + quad * 8);
            }
        }

        f32x4 acc0 = xacc;
        f32x4 acc1 = {0.f, 0.f, 0.f, 0.f};
        if (u >= 1) {
#pragma unroll
            for (int kt = 0; kt < 8; ++kt) {
                if (u < T_) acc0 = __builtin_amdgcn_mfma_f32_16x16x32_f16(a0[kt], wA[4 + kt], acc0, 0, 0, 0);
                acc1 = __builtin_amdgcn_mfma_f32_16x16x32_f16(a0[kt], wB[kt], acc1, 0, 0, 0);
            }
            if (u >= 2) {
#pragma unroll
                for (int kt = 0; kt < 8; ++kt)
                    acc1 = __builtin_amdgcn_mfma_f32_16x16x32_f16(a1[kt], wB[8 + kt], acc1, 0, 0, 0);
            }
        }

        // gates -> LDS (+bias). D-frag: value r is [m=quad*4+r][n=row]
        if (u < T_) {
#pragma unroll
            for (int r = 0; r < 4; ++r)
                gbuf[w * 256 + (quad * 4 + r) * 16 + row] = acc0[r] + biasA;
        }
        if (u >= 1) {
#pragma unroll
            for (int r = 0; r < 4; ++r)
                gbuf[1024 + w * 256 + (quad * 4 + r) * 16 + row] = acc1[r] + biasB;
        }
        __syncthreads();

        const int idx = bb * 16 + jj;
        if (u < T_) {
            float gi = fast_sig(gbuf[idx]);
            float gf = fast_sig(gbuf[256 + idx]);
            float gg = fast_tanh(gbuf[512 + idx]);
            float go = fast_sig(gbuf[768 + idx]);
            c0 = gf * c0 + gi * gg;
            float h0v = go * fast_tanh(c0);
            union { _Float16 h; unsigned short s; } cv; cv.h = (_Float16)h0v;
            store_dw_mall(h0u + ((size_t)(u & 1) * B_ + bglob) * H_ + j0 + jj,
                          ((unsigned)(u + 1) << 16) | cv.s);
        }
        if (u >= 1) {
            float gi = fast_sig(gbuf[1024 + idx]);
            float gf = fast_sig(gbuf[1024 + 256 + idx]);
            float gg = fast_tanh(gbuf[1024 + 512 + idx]);
            float go = fast_sig(gbuf[1024 + 768 + idx]);
            c1 = gf * c1 + gi * gg;
            float h1v = go * fast_tanh(c1);
            union { _Float16 h; unsigned short s; } cv; cv.h = (_Float16)h1v;
            store_dw_mall(h1u + ((size_t)((u - 1) & 1) * B_ + bglob) * H_ + j0 + jj,
                          ((unsigned)u << 16) | cv.s);
            if (u == len) hsave = h1v;
        }

        // xacc for step u+1 (overlaps store flight; consumed before next poll)
        if (u < T_ - 1) {
            const float* xp = xrow + (size_t)(u + 1) * D_;
            f32x4 t = {0.f, 0.f, 0.f, 0.f};
#pragma unroll
            for (int kt = 0; kt < 4; ++kt)
                t = __builtin_amdgcn_mfma_f32_16x16x32_f16(cvt8(xp + kt * 32), wA[kt], t, 0, 0, 0);
            xacc = t;
        }
    }

    float part = hsave * fcw[j0 + jj];
#pragma unroll
    for (int o = 1; o < 16; o <<= 1) part += __shfl_xor(part, o, 16);
    if (jj == 0) partials[sl * B_ + bglob] = part;
}

__global__ void lstm_fc(const float* __restrict__ fcb, const char* __restrict__ ws,
                        float* __restrict__ out) {
    const int b = threadIdx.x;
    const float* partials = (const float*)(ws + WS_PART);
    float s = fcb[0];
#pragma unroll
    for (int sl = 0; sl < 16; ++sl) s += partials[sl * B_ + b];
    out[b] = s;
}

extern "C" void kernel_launch(void* const* d_in, const int* in_sizes, int n_in,
                              void* d_out, int out_size, void* d_ws, size_t ws_size,
                              hipStream_t stream) {
    const float* xx    = (const float*)d_in[0];
    const int*   mask  = (const int*)d_in[1];
    const float* Wih0  = (const float*)d_in[2];
    const float* Whh0  = (const float*)d_in[3];
    const float* bih0  = (const float*)d_in[4];
    const float* bhh0  = (const float*)d_in[5];
    const float* Wih1  = (const float*)d_in[6];
    const float* Whh1  = (const float*)d_in[7];
    const float* bih1  = (const float*)d_in[8];
    const float* bhh1  = (const float*)d_in[9];
    const float* fcw   = (const float*)d_in[10];
    const float* fcb   = (const float*)d_in[11];

    lstm_main<<<dim3(256), dim3(256), 0, stream>>>(
        xx, mask, Wih0, Whh0, bih0, bhh0, Wih1, Whh1, bih1, bhh1, fcw, (char*)d_ws);
    lstm_fc<<<dim3(1), dim3(256), 0, stream>>>(fcb, (const char*)d_ws, (float*)d_out);
}

// Round 7
// 1977.586 us; speedup vs baseline: 458.1274x; 1.0187x over previous
//
#include <hip/hip_runtime.h>
#include <stdint.h>

#define B_ 256
#define T_ 512
#define D_ 128
#define H_ 256

typedef __attribute__((ext_vector_type(8))) _Float16 half8;
typedef __attribute__((ext_vector_type(4))) float f32x4;
typedef __attribute__((ext_vector_type(4))) int i32x4;

// ws layout (bytes)
#define WS_PART 0                      // 16*256 floats fc partials
#define WS_H0   65536                  // [2][256][256] u32 (epoch<<16 | f16) layer0 h
#define WS_H1   (65536 + 2*B_*H_*4)    // [2][256][256] u32 layer1 h

__device__ __forceinline__ float fast_sig(float x) {
    return 1.0f / (1.0f + __expf(-x));
}
__device__ __forceinline__ float fast_tanh(float x) {
    float xc = fminf(fmaxf(x, -30.0f), 30.0f);
    float e = __expf(-2.0f * xc);
    return (1.0f - e) / (1.0f + e);
}
__device__ __forceinline__ half8 cvt8(const float* p) {
    const f32x4* q = (const f32x4*)p;
    f32x4 a = q[0], b = q[1];
    half8 r;
    r[0] = (_Float16)a[0]; r[1] = (_Float16)a[1];
    r[2] = (_Float16)a[2]; r[3] = (_Float16)a[3];
    r[4] = (_Float16)b[0]; r[5] = (_Float16)b[1];
    r[6] = (_Float16)b[2]; r[7] = (_Float16)b[3];
    return r;
}
__device__ __forceinline__ half8 cvt8v(f32x4 a, f32x4 b) {
    half8 r;
    r[0] = (_Float16)a[0]; r[1] = (_Float16)a[1];
    r[2] = (_Float16)a[2]; r[3] = (_Float16)a[3];
    r[4] = (_Float16)b[0]; r[5] = (_Float16)b[1];
    r[6] = (_Float16)b[2]; r[7] = (_Float16)b[3];
    return r;
}

// ---- MALL-coherent (sc0 sc1) primitives — the ONLY verified cross-CU path ----
__device__ __forceinline__ void poll8(const unsigned* p0, const unsigned* p1, i32x4* r) {
    asm volatile(
        "global_load_dwordx4 %0, %8, off sc0 sc1\n\t"
        "global_load_dwordx4 %1, %8, off offset:16 sc0 sc1\n\t"
        "global_load_dwordx4 %2, %8, off offset:128 sc0 sc1\n\t"
        "global_load_dwordx4 %3, %8, off offset:144 sc0 sc1\n\t"
        "global_load_dwordx4 %4, %9, off sc0 sc1\n\t"
        "global_load_dwordx4 %5, %9, off offset:16 sc0 sc1\n\t"
        "global_load_dwordx4 %6, %9, off offset:128 sc0 sc1\n\t"
        "global_load_dwordx4 %7, %9, off offset:144 sc0 sc1\n\t"
        "s_waitcnt vmcnt(0)"
        : "=&v"(r[0]), "=&v"(r[1]), "=&v"(r[2]), "=&v"(r[3]),
          "=&v"(r[4]), "=&v"(r[5]), "=&v"(r[6]), "=&v"(r[7])
        : "v"(p0), "v"(p1) : "memory");
}
__device__ __forceinline__ void store_dw_mall(unsigned* p, unsigned v) {
    asm volatile("global_store_dword %0, %1, off sc0 sc1" :: "v"(p), "v"(v) : "memory");
}

// gbuf layout: [layer][gate][m][n], m-stride 18 (write banks 2-way, free)
#define GB_M  18
#define GB_G  (16 * GB_M)   // 288
#define GB_L  (4 * GB_G)    // 1152

// grid 256 wgs x 256 thr. wg = (batch group g = blk&15) x (hidden slice sl = blk>>4)
// wave w = gate (i,f,g,o); weights pinned in regs as f16 MFMA B-frags.
// Layer-pipelined: iter u does layer0 step u (u<T) and layer1 step u-1 (u>=1).
// Epoch-tagged h (no barriers/flags/atomics). Step is ordered so the h0->h0
// recurrence cycle (poll -> acc0 -> gates L0 -> elemwise -> store h0) is as
// short as possible; layer1 + x-precompute run in the slack after the store.
__global__ __launch_bounds__(256, 1) void lstm_main(
    const float* __restrict__ x, const int* __restrict__ mask,
    const float* __restrict__ Wih0, const float* __restrict__ Whh0,
    const float* __restrict__ bih0, const float* __restrict__ bhh0,
    const float* __restrict__ Wih1, const float* __restrict__ Whh1,
    const float* __restrict__ bih1, const float* __restrict__ bhh1,
    const float* __restrict__ fcw, char* __restrict__ ws)
{
    const int tid  = threadIdx.x;
    const int blk  = blockIdx.x;
    const int g    = blk & 15;    // batch group
    const int sl   = blk >> 4;    // hidden slice
    const int b0   = g * 16;
    const int j0   = sl * 16;
    const int w    = tid >> 6;
    const int lane = tid & 63;
    const int row  = lane & 15;
    const int quad = lane >> 4;
    const int kb   = quad * 8;

    float*    partials = (float*)(ws + WS_PART);
    unsigned* h0u      = (unsigned*)(ws + WS_H0);
    unsigned* h1u      = (unsigned*)(ws + WS_H1);

    __shared__ float gbuf[2 * GB_L];
    __shared__ __align__(16) _Float16 hsh0[16 * 264];
    __shared__ __align__(16) _Float16 hsh1[16 * 264];

    // ---- pin weights in registers (f16 B-frags), n = gate row ----
    const int n = w * H_ + j0 + row;
    half8 wA[12], wB[16];
#pragma unroll
    for (int kt = 0; kt < 4; ++kt) wA[kt]     = cvt8(&Wih0[(size_t)n * D_ + kt * 32 + kb]);
#pragma unroll
    for (int kt = 0; kt < 8; ++kt) wA[4 + kt] = cvt8(&Whh0[(size_t)n * H_ + kt * 32 + kb]);
#pragma unroll
    for (int kt = 0; kt < 8; ++kt) wB[kt]     = cvt8(&Wih1[(size_t)n * H_ + kt * 32 + kb]);
#pragma unroll
    for (int kt = 0; kt < 8; ++kt) wB[8 + kt] = cvt8(&Whh1[(size_t)n * H_ + kt * 32 + kb]);
    const float biasA = bih0[n] + bhh0[n];
    const float biasB = bih1[n] + bhh1[n];

    const int bb    = tid >> 4;
    const int jj    = tid & 15;
    const int bglob = b0 + bb;

    int len = 0;
    {
        const int* mrow = mask + (size_t)bglob * T_ + jj * 32;
#pragma unroll
        for (int q = 0; q < 32; ++q) len += mrow[q];
#pragma unroll
        for (int o = 1; o < 16; o <<= 1) len += __shfl_xor(len, o, 16);
    }

    float c0 = 0.f, c1 = 0.f, hsave = 0.f;

    const float* xrow = x + (size_t)(b0 + row) * T_ * D_ + kb;
    // xacc for step 0
    f32x4 xacc = {0.f, 0.f, 0.f, 0.f};
#pragma unroll
    for (int kt = 0; kt < 4; ++kt)
        xacc = __builtin_amdgcn_mfma_f32_16x16x32_f16(cvt8(xrow + kt * 32), wA[kt], xacc, 0, 0, 0);

    for (int u = 0; u <= T_; ++u) {
        // ---- x prefetch for step u+1 into registers (completes under poll) ----
        f32x4 xr[8];
        {
            const int tn = (u + 1 < T_) ? (u + 1) : (T_ - 1);
            const f32x4* q = (const f32x4*)(xrow + (size_t)tn * D_);
#pragma unroll
            for (int kt = 0; kt < 4; ++kt) { xr[2 * kt] = q[kt * 8]; xr[2 * kt + 1] = q[kt * 8 + 1]; }
        }

        half8 a0[8], a1[8];
        if (u >= 1) {
            // ---- poll this wave's quarter of h0[u-1] + h1[u-2] ----
            const unsigned tag0 = (unsigned)u << 16;
            const unsigned tag1 = (u >= 2) ? ((unsigned)(u - 1) << 16) : tag0;
            const unsigned* p0 = h0u + ((size_t)((u - 1) & 1) * B_ + (b0 + row)) * H_ + w * 64 + quad * 8;
            const unsigned* p1 = (u >= 2)
                ? h1u + ((size_t)(u & 1) * B_ + (b0 + row)) * H_ + w * 64 + quad * 8
                : p0;
            i32x4 r[8];
            int guard = 0;
            while (true) {
                poll8(p0, p1, r);
                unsigned m = 0;
#pragma unroll
                for (int i = 0; i < 4; ++i) {
                    m |= ((unsigned)r[i][0] ^ tag0); m |= ((unsigned)r[i][1] ^ tag0);
                    m |= ((unsigned)r[i][2] ^ tag0); m |= ((unsigned)r[i][3] ^ tag0);
                }
#pragma unroll
                for (int i = 4; i < 8; ++i) {
                    m |= ((unsigned)r[i][0] ^ tag1); m |= ((unsigned)r[i][1] ^ tag1);
                    m |= ((unsigned)r[i][2] ^ tag1); m |= ((unsigned)r[i][3] ^ tag1);
                }
                if (__all((m & 0xFFFF0000u) == 0)) break;
                if (++guard > (1 << 15)) break;  // bounded: fail loud, never hang
            }
            // ---- unpack payloads -> LDS ----
#pragma unroll
            for (int t = 0; t < 2; ++t) {
                i32x4 pk;
                pk[0] = (r[2 * t][0] & 0xFFFF) | (r[2 * t][1] << 16);
                pk[1] = (r[2 * t][2] & 0xFFFF) | (r[2 * t][3] << 16);
                pk[2] = (r[2 * t + 1][0] & 0xFFFF) | (r[2 * t + 1][1] << 16);
                pk[3] = (r[2 * t + 1][2] & 0xFFFF) | (r[2 * t + 1][3] << 16);
                *(i32x4*)(hsh0 + row * 264 + w * 64 + t * 32 + quad * 8) = pk;
            }
            if (u >= 2) {
#pragma unroll
                for (int t = 0; t < 2; ++t) {
                    i32x4 pk;
                    pk[0] = (r[4 + 2 * t][0] & 0xFFFF) | (r[4 + 2 * t][1] << 16);
                    pk[1] = (r[4 + 2 * t][2] & 0xFFFF) | (r[4 + 2 * t][3] << 16);
                    pk[2] = (r[5 + 2 * t][0] & 0xFFFF) | (r[5 + 2 * t][1] << 16);
                    pk[3] = (r[5 + 2 * t][2] & 0xFFFF) | (r[5 + 2 * t][3] << 16);
                    *(i32x4*)(hsh1 + row * 264 + w * 64 + t * 32 + quad * 8) = pk;
                }
            }
            __syncthreads();  // sync #1: hsh complete
            // read ALL cross-step LDS data now (rigorous WAR: these reads
            // happen-before own h stores -> before any peer's next-step write)
#pragma unroll
            for (int kt = 0; kt < 8; ++kt)
                a0[kt] = *(const half8*)(hsh0 + row * 264 + kt * 32 + quad * 8);
            if (u >= 2) {
#pragma unroll
                for (int kt = 0; kt < 8; ++kt)
                    a1[kt] = *(const half8*)(hsh1 + row * 264 + kt * 32 + quad * 8);
            }
        }

        // ================= layer 0 (critical recurrence) =================
        if (u < T_) {
            f32x4 acc0 = xacc;
            if (u >= 1) {
#pragma unroll
                for (int kt = 0; kt < 8; ++kt)
                    acc0 = __builtin_amdgcn_mfma_f32_16x16x32_f16(a0[kt], wA[4 + kt], acc0, 0, 0, 0);
            }
#pragma unroll
            for (int r = 0; r < 4; ++r)
                gbuf[w * GB_G + (quad * 4 + r) * GB_M + row] = acc0[r] + biasA;
            __syncthreads();  // sync #2: gbuf L0 ready
            float gi = fast_sig(gbuf[0 * GB_G + bb * GB_M + jj]);
            float gf = fast_sig(gbuf[1 * GB_G + bb * GB_M + jj]);
            float gg = fast_tanh(gbuf[2 * GB_G + bb * GB_M + jj]);
            float go = fast_sig(gbuf[3 * GB_G + bb * GB_M + jj]);
            c0 = gf * c0 + gi * gg;
            float h0v = go * fast_tanh(c0);
            union { _Float16 h; unsigned short s; } cv; cv.h = (_Float16)h0v;
            store_dw_mall(h0u + ((size_t)(u & 1) * B_ + bglob) * H_ + j0 + jj,
                          ((unsigned)(u + 1) << 16) | cv.s);  // h0[u] fires EARLY
        }
        __builtin_amdgcn_sched_barrier(0);  // keep layer1 work below the store

        // ================= layer 1 (one step of slack) =================
        if (u >= 1) {
            f32x4 acc1 = {0.f, 0.f, 0.f, 0.f};
#pragma unroll
            for (int kt = 0; kt < 8; ++kt)
                acc1 = __builtin_amdgcn_mfma_f32_16x16x32_f16(a0[kt], wB[kt], acc1, 0, 0, 0);
            if (u >= 2) {
#pragma unroll
                for (int kt = 0; kt < 8; ++kt)
                    acc1 = __builtin_amdgcn_mfma_f32_16x16x32_f16(a1[kt], wB[8 + kt], acc1, 0, 0, 0);
            }
#pragma unroll
            for (int r = 0; r < 4; ++r)
                gbuf[GB_L + w * GB_G + (quad * 4 + r) * GB_M + row] = acc1[r] + biasB;
            __syncthreads();  // sync #3: gbuf L1 ready
            float gi = fast_sig(gbuf[GB_L + 0 * GB_G + bb * GB_M + jj]);
            float gf = fast_sig(gbuf[GB_L + 1 * GB_G + bb * GB_M + jj]);
            float gg = fast_tanh(gbuf[GB_L + 2 * GB_G + bb * GB_M + jj]);
            float go = fast_sig(gbuf[GB_L + 3 * GB_G + bb * GB_M + jj]);
            c1 = gf * c1 + gi * gg;
            float h1v = go * fast_tanh(c1);
            union { _Float16 h; unsigned short s; } cv; cv.h = (_Float16)h1v;
            store_dw_mall(h1u + ((size_t)((u - 1) & 1) * B_ + bglob) * H_ + j0 + jj,
                          ((unsigned)u << 16) | cv.s);
            if (u == len) hsave = h1v;
        }

        // xacc for step u+1 (slack; xr already in registers)
        if (u < T_ - 1) {
            f32x4 t = {0.f, 0.f, 0.f, 0.f};
#pragma unroll
            for (int kt = 0; kt < 4; ++kt)
                t = __builtin_amdgcn_mfma_f32_16x16x32_f16(cvt8v(xr[2 * kt], xr[2 * kt + 1]), wA[kt], t, 0, 0, 0);
            xacc = t;
        }
    }

    float part = hsave * fcw[j0 + jj];
#pragma unroll
    for (int o = 1; o < 16; o <<= 1) part += __shfl_xor(part, o, 16);
    if (jj == 0) partials[sl * B_ + bglob] = part;
}

__global__ void lstm_fc(const float* __restrict__ fcb, const char* __restrict__ ws,
                        float* __restrict__ out) {
    const int b = threadIdx.x;
    const float* partials = (const float*)(ws + WS_PART);
    float s = fcb[0];
#pragma unroll
    for (int sl = 0; sl < 16; ++sl) s += partials[sl * B_ + b];
    out[b] = s;
}

extern "C" void kernel_launch(void* const* d_in, const int* in_sizes, int n_in,
                              void* d_out, int out_size, void* d_ws, size_t ws_size,
                              hipStream_t stream) {
    const float* xx    = (const float*)d_in[0];
    const int*   mask  = (const int*)d_in[1];
    const float* Wih0  = (const float*)d_in[2];
    const float* Whh0  = (const float*)d_in[3];
    const float* bih0  = (const float*)d_in[4];
    const float* bhh0  = (const float*)d_in[5];
    const float* Wih1  = (const float*)d_in[6];
    const float* Whh1  = (const float*)d_in[7];
    const float* bih1  = (const float*)d_in[8];
    const float* bhh1  = (const float*)d_in[9];
    const float* fcw   = (const float*)d_in[10];
    const float* fcb   = (const float*)d_in[11];

    lstm_main<<<dim3(256), dim3(256), 0, stream>>>(
        xx, mask, Wih0, Whh0, bih0, bhh0, Wih1, Whh1, bih1, bhh1, fcw, (char*)d_ws);
    lstm_fc<<<dim3(1), dim3(256), 0, stream>>>(fcb, (const char*)d_ws, (float*)d_out);
}

// Round 8
// 1709.158 us; speedup vs baseline: 530.0775x; 1.1571x over previous
//
#include <hip/hip_runtime.h>
#include <stdint.h>

#define B_ 256
#define T_ 512
#define D_ 128
#define H_ 256

typedef __attribute__((ext_vector_type(8))) _Float16 half8;
typedef __attribute__((ext_vector_type(4))) float f32x4;
typedef __attribute__((ext_vector_type(4))) int i32x4;

// ws layout (bytes)
#define WS_PART 0                      // 16*256 floats fc partials
#define WS_H0   65536                  // [2][256][256] u32 (epoch<<16 | f16) layer0 h
#define WS_H1   (65536 + 2*B_*H_*4)    // [2][256][256] u32 layer1 h

__device__ __forceinline__ float fast_sig(float x) {
    return 1.0f / (1.0f + __expf(-x));
}
__device__ __forceinline__ float fast_tanh(float x) {
    float xc = fminf(fmaxf(x, -30.0f), 30.0f);
    float e = __expf(-2.0f * xc);
    return (1.0f - e) / (1.0f + e);
}
__device__ __forceinline__ half8 cvt8(const float* p) {
    const f32x4* q = (const f32x4*)p;
    f32x4 a = q[0], b = q[1];
    half8 r;
    r[0] = (_Float16)a[0]; r[1] = (_Float16)a[1];
    r[2] = (_Float16)a[2]; r[3] = (_Float16)a[3];
    r[4] = (_Float16)b[0]; r[5] = (_Float16)b[1];
    r[6] = (_Float16)b[2]; r[7] = (_Float16)b[3];
    return r;
}
__device__ __forceinline__ half8 cvt8v(f32x4 a, f32x4 b) {
    half8 r;
    r[0] = (_Float16)a[0]; r[1] = (_Float16)a[1];
    r[2] = (_Float16)a[2]; r[3] = (_Float16)a[3];
    r[4] = (_Float16)b[0]; r[5] = (_Float16)b[1];
    r[6] = (_Float16)b[2]; r[7] = (_Float16)b[3];
    return r;
}

// ---- MALL-coherent (sc0 sc1) primitives — the ONLY verified cross-CU path ----
// Fire-and-forget issue of one 4-tile snapshot (no wait).
__device__ __forceinline__ void poll4_issue(const unsigned* p, i32x4* r) {
    asm volatile(
        "global_load_dwordx4 %0, %4, off sc0 sc1\n\t"
        "global_load_dwordx4 %1, %4, off offset:16 sc0 sc1\n\t"
        "global_load_dwordx4 %2, %4, off offset:128 sc0 sc1\n\t"
        "global_load_dwordx4 %3, %4, off offset:144 sc0 sc1"
        : "=&v"(r[0]), "=&v"(r[1]), "=&v"(r[2]), "=&v"(r[3])
        : "v"(p) : "memory");
}
// Blocking re-poll (issue + wait in one asm: values valid on return).
__device__ __forceinline__ void poll4_wait(const unsigned* p, i32x4* r) {
    asm volatile(
        "global_load_dwordx4 %0, %4, off sc0 sc1\n\t"
        "global_load_dwordx4 %1, %4, off offset:16 sc0 sc1\n\t"
        "global_load_dwordx4 %2, %4, off offset:128 sc0 sc1\n\t"
        "global_load_dwordx4 %3, %4, off offset:144 sc0 sc1\n\t"
        "s_waitcnt vmcnt(0)"
        : "=&v"(r[0]), "=&v"(r[1]), "=&v"(r[2]), "=&v"(r[3])
        : "v"(p) : "memory");
}
// Single wait that ties BOTH pre-issued snapshots into dataflow (so no
// consumer of r0/r1 can be scheduled before the waitcnt).
__device__ __forceinline__ void wait_tie8(i32x4* a, i32x4* b) {
    asm volatile("s_waitcnt vmcnt(0)"
        : "+v"(a[0]), "+v"(a[1]), "+v"(a[2]), "+v"(a[3]),
          "+v"(b[0]), "+v"(b[1]), "+v"(b[2]), "+v"(b[3]) :: "memory");
}
__device__ __forceinline__ void store_dw_mall(unsigned* p, unsigned v) {
    asm volatile("global_store_dword %0, %1, off sc0 sc1" :: "v"(p), "v"(v) : "memory");
}

__device__ __forceinline__ int tags_ok(const i32x4* r, unsigned tag) {
    unsigned m = 0;
#pragma unroll
    for (int i = 0; i < 4; ++i) {
        m |= ((unsigned)r[i][0] ^ tag); m |= ((unsigned)r[i][1] ^ tag);
        m |= ((unsigned)r[i][2] ^ tag); m |= ((unsigned)r[i][3] ^ tag);
    }
    return __all((m & 0xFFFF0000u) == 0);
}
// unpack 4-tile snapshot payloads -> LDS rows (wave's 2 k-tiles)
__device__ __forceinline__ void unpack_to_lds(const i32x4* r, _Float16* base) {
#pragma unroll
    for (int t = 0; t < 2; ++t) {
        i32x4 pk;
        pk[0] = (r[2 * t][0] & 0xFFFF) | (r[2 * t][1] << 16);
        pk[1] = (r[2 * t][2] & 0xFFFF) | (r[2 * t][3] << 16);
        pk[2] = (r[2 * t + 1][0] & 0xFFFF) | (r[2 * t + 1][1] << 16);
        pk[3] = (r[2 * t + 1][2] & 0xFFFF) | (r[2 * t + 1][3] << 16);
        *(i32x4*)(base + t * 32) = pk;
    }
}

// grid 256 wgs x 256 thr. wg = (batch group g = blk&15) x (hidden slice sl = blk>>4)
// wave w = gate (i,f,g,o); weights pinned in regs as f16 MFMA B-frags.
// Layer-pipelined: iter u does layer0 step u (u<T) and layer1 step u-1 (u>=1).
// Epoch-tagged h at MALL; polls are SOFTWARE-PIPELINED: next step's snapshot
// loads are fired at the end of the current step, so the step entry is one
// vmcnt(0) + register tag-check (no extra round trip when peers are on time).
__global__ __launch_bounds__(256, 1) void lstm_main(
    const float* __restrict__ x, const int* __restrict__ mask,
    const float* __restrict__ Wih0, const float* __restrict__ Whh0,
    const float* __restrict__ bih0, const float* __restrict__ bhh0,
    const float* __restrict__ Wih1, const float* __restrict__ Whh1,
    const float* __restrict__ bih1, const float* __restrict__ bhh1,
    const float* __restrict__ fcw, char* __restrict__ ws)
{
    const int tid  = threadIdx.x;
    const int blk  = blockIdx.x;
    const int g    = blk & 15;    // batch group
    const int sl   = blk >> 4;    // hidden slice
    const int b0   = g * 16;
    const int j0   = sl * 16;
    const int w    = tid >> 6;
    const int lane = tid & 63;
    const int row  = lane & 15;
    const int quad = lane >> 4;
    const int kb   = quad * 8;

    float*    partials = (float*)(ws + WS_PART);
    unsigned* h0u      = (unsigned*)(ws + WS_H0);
    unsigned* h1u      = (unsigned*)(ws + WS_H1);

    __shared__ float gbuf[2048];
    __shared__ __align__(16) _Float16 hsh0[16 * 264];
    __shared__ __align__(16) _Float16 hsh1[16 * 264];

    // ---- pin weights in registers (f16 B-frags), n = gate row ----
    const int n = w * H_ + j0 + row;
    half8 wA[12], wB[16];
#pragma unroll
    for (int kt = 0; kt < 4; ++kt) wA[kt]     = cvt8(&Wih0[(size_t)n * D_ + kt * 32 + kb]);
#pragma unroll
    for (int kt = 0; kt < 8; ++kt) wA[4 + kt] = cvt8(&Whh0[(size_t)n * H_ + kt * 32 + kb]);
#pragma unroll
    for (int kt = 0; kt < 8; ++kt) wB[kt]     = cvt8(&Wih1[(size_t)n * H_ + kt * 32 + kb]);
#pragma unroll
    for (int kt = 0; kt < 8; ++kt) wB[8 + kt] = cvt8(&Whh1[(size_t)n * H_ + kt * 32 + kb]);
    const float biasA = bih0[n] + bhh0[n];
    const float biasB = bih1[n] + bhh1[n];

    const int bb    = tid >> 4;
    const int jj    = tid & 15;
    const int bglob = b0 + bb;

    int len = 0;
    {
        const int* mrow = mask + (size_t)bglob * T_ + jj * 32;
#pragma unroll
        for (int q = 0; q < 32; ++q) len += mrow[q];
#pragma unroll
        for (int o = 1; o < 16; o <<= 1) len += __shfl_xor(len, o, 16);
    }

    float c0 = 0.f, c1 = 0.f, hsave = 0.f;

    const float* xrow = x + (size_t)(b0 + row) * T_ * D_ + kb;
    // xacc for step 0
    f32x4 xacc = {0.f, 0.f, 0.f, 0.f};
#pragma unroll
    for (int kt = 0; kt < 4; ++kt)
        xacc = __builtin_amdgcn_mfma_f32_16x16x32_f16(cvt8(xrow + kt * 32), wA[kt], xacc, 0, 0, 0);

    i32x4 r0[4], r1[4];   // pre-issued h0 / h1 snapshots
    const int koff = w * 64 + quad * 8;  // this wave's k-quarter (u32 units)

    for (int u = 0; u <= T_; ++u) {
        half8 a0[8], a1[8];
        f32x4 xr[8];
        int h1ok = 1;
        const unsigned tag1 = (unsigned)(u - 1) << 16;

        if (u >= 1) {
            // ---- step entry: ONE wait covering store-acks + both snapshots ----
            wait_tie8(r0, r1);
            const unsigned tag0 = (unsigned)u << 16;
            const unsigned* p0 = h0u + ((size_t)((u - 1) & 1) * B_ + (b0 + row)) * H_ + koff;
            int guard = 0;
            while (!tags_ok(r0, tag0)) {
                poll4_wait(p0, r0);
                if (++guard > (1 << 15)) break;  // bounded: fail loud, never hang
            }
            h1ok = (u >= 2) ? tags_ok(r1, tag1) : 1;
            // x prefetch for u+1 (plain cached loads; latency hidden in slack)
            {
                const int tn = (u + 1 < T_) ? (u + 1) : (T_ - 1);
                const f32x4* q = (const f32x4*)(xrow + (size_t)tn * D_);
#pragma unroll
                for (int kt = 0; kt < 4; ++kt) { xr[2 * kt] = q[kt * 8]; xr[2 * kt + 1] = q[kt * 8 + 1]; }
            }
            // unpack h0 -> LDS, share across waves, read A-frags
            unpack_to_lds(r0, hsh0 + row * 264 + koff);
            __syncthreads();  // sync A
#pragma unroll
            for (int kt = 0; kt < 8; ++kt)
                a0[kt] = *(const half8*)(hsh0 + row * 264 + kt * 32 + quad * 8);
        } else {
            const f32x4* q = (const f32x4*)(xrow + (size_t)1 * D_);
#pragma unroll
            for (int kt = 0; kt < 4; ++kt) { xr[2 * kt] = q[kt * 8]; xr[2 * kt + 1] = q[kt * 8 + 1]; }
        }

        // ================= layer 0 (critical recurrence) =================
        if (u < T_) {
            f32x4 acc0 = xacc;
            if (u >= 1) {
#pragma unroll
                for (int kt = 0; kt < 8; ++kt)
                    acc0 = __builtin_amdgcn_mfma_f32_16x16x32_f16(a0[kt], wA[4 + kt], acc0, 0, 0, 0);
            }
#pragma unroll
            for (int r = 0; r < 4; ++r)
                gbuf[w * 256 + (quad * 4 + r) * 16 + row] = acc0[r] + biasA;
            __syncthreads();  // sync B
            const int idx = bb * 16 + jj;
            float gi = fast_sig(gbuf[idx]);
            float gf = fast_sig(gbuf[256 + idx]);
            float gg = fast_tanh(gbuf[512 + idx]);
            float go = fast_sig(gbuf[768 + idx]);
            c0 = gf * c0 + gi * gg;
            float h0v = go * fast_tanh(c0);
            union { _Float16 h; unsigned short s; } cv; cv.h = (_Float16)h0v;
            store_dw_mall(h0u + ((size_t)(u & 1) * B_ + bglob) * H_ + j0 + jj,
                          ((unsigned)(u + 1) << 16) | cv.s);  // h0[u] fires EARLY
        }
        __builtin_amdgcn_sched_barrier(0);  // keep layer1 below the h0 store

        // ================= layer 1 (one step of slack) =================
        if (u >= 1) {
            f32x4 acc1 = {0.f, 0.f, 0.f, 0.f};
#pragma unroll
            for (int kt = 0; kt < 8; ++kt)
                acc1 = __builtin_amdgcn_mfma_f32_16x16x32_f16(a0[kt], wB[kt], acc1, 0, 0, 0);
            if (u >= 2) {
                const unsigned* p1 = h1u + ((size_t)(u & 1) * B_ + (b0 + row)) * H_ + koff;
                int guard = 0;
                while (!h1ok) {        // rare: slack absorbs the re-poll
                    poll4_wait(p1, r1);
                    h1ok = tags_ok(r1, tag1);
                    if (++guard > (1 << 15)) break;
                }
                unpack_to_lds(r1, hsh1 + row * 264 + koff);
                __syncthreads();  // sync C
#pragma unroll
                for (int kt = 0; kt < 8; ++kt)
                    a1[kt] = *(const half8*)(hsh1 + row * 264 + kt * 32 + quad * 8);
#pragma unroll
                for (int kt = 0; kt < 8; ++kt)
                    acc1 = __builtin_amdgcn_mfma_f32_16x16x32_f16(a1[kt], wB[8 + kt], acc1, 0, 0, 0);
            }
#pragma unroll
            for (int r = 0; r < 4; ++r)
                gbuf[1024 + w * 256 + (quad * 4 + r) * 16 + row] = acc1[r] + biasB;
            __syncthreads();  // sync D
            const int idx = bb * 16 + jj;
            float gi = fast_sig(gbuf[1024 + idx]);
            float gf = fast_sig(gbuf[1024 + 256 + idx]);
            float gg = fast_tanh(gbuf[1024 + 512 + idx]);
            float go = fast_sig(gbuf[1024 + 768 + idx]);
            c1 = gf * c1 + gi * gg;
            float h1v = go * fast_tanh(c1);
            union { _Float16 h; unsigned short s; } cv; cv.h = (_Float16)h1v;
            store_dw_mall(h1u + ((size_t)((u - 1) & 1) * B_ + bglob) * H_ + j0 + jj,
                          ((unsigned)u << 16) | cv.s);
            if (u == len) hsave = h1v;
        }

        // ---- pre-issue next step's snapshots (fire-and-forget) ----
        if (u < T_) {
            const int v = u + 1;
            const unsigned* q0 = h0u + ((size_t)((v - 1) & 1) * B_ + (b0 + row)) * H_ + koff;
            const unsigned* q1 = (v >= 2)
                ? h1u + ((size_t)(v & 1) * B_ + (b0 + row)) * H_ + koff
                : q0;
            poll4_issue(q0, r0);
            poll4_issue(q1, r1);
        }

        // xacc for step u+1 (xr regs; compiler inserts the needed vmcnt)
        if (u < T_ - 1) {
            f32x4 t = {0.f, 0.f, 0.f, 0.f};
#pragma unroll
            for (int kt = 0; kt < 4; ++kt)
                t = __builtin_amdgcn_mfma_f32_16x16x32_f16(cvt8v(xr[2 * kt], xr[2 * kt + 1]), wA[kt], t, 0, 0, 0);
            xacc = t;
        }
    }

    float part = hsave * fcw[j0 + jj];
#pragma unroll
    for (int o = 1; o < 16; o <<= 1) part += __shfl_xor(part, o, 16);
    if (jj == 0) partials[sl * B_ + bglob] = part;
}

__global__ void lstm_fc(const float* __restrict__ fcb, const char* __restrict__ ws,
                        float* __restrict__ out) {
    const int b = threadIdx.x;
    const float* partials = (const float*)(ws + WS_PART);
    float s = fcb[0];
#pragma unroll
    for (int sl = 0; sl < 16; ++sl) s += partials[sl * B_ + b];
    out[b] = s;
}

extern "C" void kernel_launch(void* const* d_in, const int* in_sizes, int n_in,
                              void* d_out, int out_size, void* d_ws, size_t ws_size,
                              hipStream_t stream) {
    const float* xx    = (const float*)d_in[0];
    const int*   mask  = (const int*)d_in[1];
    const float* Wih0  = (const float*)d_in[2];
    const float* Whh0  = (const float*)d_in[3];
    const float* bih0  = (const float*)d_in[4];
    const float* bhh0  = (const float*)d_in[5];
    const float* Wih1  = (const float*)d_in[6];
    const float* Whh1  = (const float*)d_in[7];
    const float* bih1  = (const float*)d_in[8];
    const float* bhh1  = (const float*)d_in[9];
    const float* fcw   = (const float*)d_in[10];
    const float* fcb   = (const float*)d_in[11];

    lstm_main<<<dim3(256), dim3(256), 0, stream>>>(
        xx, mask, Wih0, Whh0, bih0, bhh0, Wih1, Whh1, bih1, bhh1, fcw, (char*)d_ws);
    lstm_fc<<<dim3(1), dim3(256), 0, stream>>>(fcb, (const char*)d_ws, (float*)d_out);
}